// Round 5
// baseline (351.497 us; speedup 1.0000x reference)
//
#include <hip/hip_runtime.h>

#define NB 2
#define NH 16
#define SEQ 2048
#define DMODEL 1024
#define DHEAD 64
// 0.125 (1/sqrt(DH)) / ln(2): folded into Wq so softmax is a bare exp2
#define QSCALE 0.18033688f

typedef __attribute__((ext_vector_type(8))) short bf16x8;
typedef __attribute__((ext_vector_type(4))) short bf16x4;
typedef __attribute__((ext_vector_type(4))) float f32x4;
typedef __attribute__((ext_vector_type(16))) float f32x16;
typedef __attribute__((ext_vector_type(4))) int i32x4;

static __device__ __forceinline__ unsigned short f2bf(float f) {
    unsigned int u = __float_as_uint(f);
    u += 0x7fffu + ((u >> 16) & 1u);   // RNE
    return (unsigned short)(u >> 16);
}
static __device__ __forceinline__ unsigned int pk2(float lo, float hi) {
    return (unsigned int)f2bf(lo) | ((unsigned int)f2bf(hi) << 16);
}
static __device__ __forceinline__ void gld_lds16(const unsigned short* g, unsigned short* l) {
    __builtin_amdgcn_global_load_lds(
        (const __attribute__((address_space(1))) unsigned int*)g,
        (__attribute__((address_space(3))) unsigned int*)l, 16, 0, 0);
}

// =====================================================================
// Prep A: pack bool mask (int32) into u64 bitmask words per (b,s) row.
// =====================================================================
__global__ __launch_bounds__(256) void pack_mask_kernel(
    const int* __restrict__ mask, unsigned long long* __restrict__ mpack)
{
    const int wave = blockIdx.x * 4 + (threadIdx.x >> 6);
    const int lane = threadIdx.x & 63;
    const int* row = mask + (size_t)wave * SEQ;
    unsigned long long* orow = mpack + (size_t)wave * (SEQ / 64);
    for (int w = 0; w < SEQ / 64; ++w) {
        int m = row[w * 64 + lane];
        unsigned long long bits = __ballot(m != 0);
        if (lane == 0) orow[w] = bits;
    }
}

// =====================================================================
// Prep B1: fused Wq/Wk/Wv transpose+cvt (per head 1024x64 -> 64x1024).
// Wq additionally scaled by QSCALE. grid (16, 48).
// =====================================================================
__global__ __launch_bounds__(256) void transpose_qkv_kernel(
    const float* __restrict__ Wq, const float* __restrict__ Wk, const float* __restrict__ Wv,
    unsigned short* __restrict__ Wqt, unsigned short* __restrict__ Wkt, unsigned short* __restrict__ Wvt)
{
    const int z = blockIdx.y, sel = z >> 4, h = z & 15;
    const float* S = (sel == 0 ? Wq : sel == 1 ? Wk : Wv) + (size_t)h * DMODEL * DHEAD;
    unsigned short* D = (sel == 0 ? Wqt : sel == 1 ? Wkt : Wvt) + (size_t)h * DMODEL * DHEAD;
    const float scale = (sel == 0) ? QSCALE : 1.0f;
    const int tile_r = blockIdx.x * 64;
    __shared__ float Ls[64][65];
    const int t = threadIdx.x;
    const int c4 = (t & 15) * 4;
    for (int rr = t >> 4; rr < 64; rr += 16) {
        float4 v = *(const float4*)(S + (size_t)(tile_r + rr) * DHEAD + c4);
        Ls[rr][c4 + 0] = v.x; Ls[rr][c4 + 1] = v.y;
        Ls[rr][c4 + 2] = v.z; Ls[rr][c4 + 3] = v.w;
    }
    __syncthreads();
    const int r4 = (t & 15) * 4;
    for (int cc = t >> 4; cc < 64; cc += 16) {
        ushort4 o;
        o.x = f2bf(Ls[r4 + 0][cc] * scale); o.y = f2bf(Ls[r4 + 1][cc] * scale);
        o.z = f2bf(Ls[r4 + 2][cc] * scale); o.w = f2bf(Ls[r4 + 3][cc] * scale);
        *(ushort4*)(D + (size_t)cc * DMODEL + tile_r + r4) = o;
    }
}

// =====================================================================
// Prep B2: Wo transpose+cvt (1024x1024). grid (16, 16).
// =====================================================================
__global__ __launch_bounds__(256) void transpose_wo_kernel(
    const float* __restrict__ src, unsigned short* __restrict__ dst)
{
    const int tile_c = blockIdx.x * 64, tile_r = blockIdx.y * 64;
    __shared__ float Ls[64][65];
    const int t = threadIdx.x;
    const int c4 = (t & 15) * 4;
    for (int rr = t >> 4; rr < 64; rr += 16) {
        float4 v = *(const float4*)(src + (size_t)(tile_r + rr) * DMODEL + tile_c + c4);
        Ls[rr][c4 + 0] = v.x; Ls[rr][c4 + 1] = v.y;
        Ls[rr][c4 + 2] = v.z; Ls[rr][c4 + 3] = v.w;
    }
    __syncthreads();
    const int r4 = (t & 15) * 4;
    for (int cc = t >> 4; cc < 64; cc += 16) {
        ushort4 o;
        o.x = f2bf(Ls[r4 + 0][cc]); o.y = f2bf(Ls[r4 + 1][cc]);
        o.z = f2bf(Ls[r4 + 2][cc]); o.w = f2bf(Ls[r4 + 3][cc]);
        *(ushort4*)(dst + (size_t)(tile_c + cc) * DMODEL + tile_r + r4) = o;
    }
}

// =====================================================================
// Fused projection GEMM, XCD-swizzled 1D grid (768 blocks):
// xcd=bid&7 owns 12 consecutive m-tiles; n-tile fastest within an XCD so
// the 512KB f32 A row-block stays in that XCD's L2 across its 8 n-tiles.
// =====================================================================
__global__ __launch_bounds__(256) void proj_gemm_kernel(
    const float* __restrict__ q, const float* __restrict__ k, const float* __restrict__ v,
    const unsigned short* __restrict__ Wqt, const unsigned short* __restrict__ Wkt,
    const unsigned short* __restrict__ Wvt,
    unsigned short* __restrict__ qh, unsigned short* __restrict__ kh,
    unsigned short* __restrict__ vt)
{
    const int bid = blockIdx.x;
    const int sx = bid >> 3;                       // 0..95
    const int mtg = (bid & 7) * 12 + (sx >> 3);    // 0..95 global m-tile
    const int z = mtg >> 5;                        // 0..2
    const int m0 = (mtg & 31) * 128;
    const int n0 = (sx & 7) * 128;

    const float* A = (z == 0) ? q : (z == 1) ? k : v;
    const unsigned short* Bt = (z == 0) ? Wqt : (z == 1) ? Wkt : Wvt;

    const int t = threadIdx.x, lane = t & 63, w = t >> 6;
    const int lg = lane >> 4, ln = lane & 15;
    const int wx = w & 1, wy = w >> 1;

    __shared__ __align__(16) unsigned short As[128 * 64];
    __shared__ __align__(16) unsigned short Bs[128 * 64];

    f32x4 acc[4][4] = {};

    for (int kk = 0; kk < DMODEL; kk += 64) {
        #pragma unroll
        for (int i = 0; i < 4; ++i) {
            int s = (w * 4 + i) * 64 + lane;
            int n = s >> 3, c = (s & 7) ^ (n & 7);
            gld_lds16(Bt + (size_t)(n0 + n) * DMODEL + kk + c * 8, Bs + (size_t)s * 8);
        }
        {
            const int row = t >> 1, kh2 = (t & 1) * 32;
            const float* Ag = A + (size_t)(m0 + row) * DMODEL + kk + kh2;
            #pragma unroll
            for (int j = 0; j < 4; ++j) {
                float4 x0 = *(const float4*)(Ag + j * 8);
                float4 x1 = *(const float4*)(Ag + j * 8 + 4);
                uint4 val;
                val.x = pk2(x0.x, x0.y); val.y = pk2(x0.z, x0.w);
                val.z = pk2(x1.x, x1.y); val.w = pk2(x1.z, x1.w);
                int c = (kh2 >> 3) + j;
                *(uint4*)(As + row * 64 + ((c ^ (row & 7)) * 8)) = val;
            }
        }
        __syncthreads();
        #pragma unroll
        for (int ks = 0; ks < 2; ++ks) {
            bf16x8 af[4], bf[4];
            #pragma unroll
            for (int rb = 0; rb < 4; ++rb) {
                int r = wy * 64 + rb * 16 + ln;
                af[rb] = *(const bf16x8*)(As + r * 64 + (((ks * 4 + lg) ^ (r & 7)) * 8));
            }
            #pragma unroll
            for (int nb = 0; nb < 4; ++nb) {
                int n = wx * 64 + nb * 16 + ln;
                bf[nb] = *(const bf16x8*)(Bs + n * 64 + (((ks * 4 + lg) ^ (n & 7)) * 8));
            }
            #pragma unroll
            for (int rb = 0; rb < 4; ++rb)
                #pragma unroll
                for (int nb = 0; nb < 4; ++nb)
                    acc[rb][nb] = __builtin_amdgcn_mfma_f32_16x16x32_bf16(
                        af[rb], bf[nb], acc[rb][nb], 0, 0, 0);
        }
        __syncthreads();
    }

    if (z < 2) {
        unsigned short* Y = (z == 0) ? qh : kh;   // [bh][s][dh]
        #pragma unroll
        for (int rb = 0; rb < 4; ++rb)
            #pragma unroll
            for (int nb = 0; nb < 4; ++nb)
                #pragma unroll
                for (int r = 0; r < 4; ++r) {
                    int grow = m0 + wy * 64 + rb * 16 + lg * 4 + r;   // b*2048+s
                    int gcol = n0 + wx * 64 + nb * 16 + ln;           // h*64+e
                    size_t idx = ((size_t)((grow >> 11) * NH + (gcol >> 6)) * SEQ
                                  + (grow & (SEQ - 1))) * DHEAD + (gcol & 63);
                    Y[idx] = f2bf(acc[rb][nb][r]);
                }
    } else {
        // V transposed: vt[bh][dh][seq]
        #pragma unroll
        for (int rb = 0; rb < 4; ++rb)
            #pragma unroll
            for (int nb = 0; nb < 4; ++nb) {
                int grow0 = m0 + wy * 64 + rb * 16 + lg * 4;          // b*2048+s (s%4==0)
                int gcol  = n0 + wx * 64 + nb * 16 + ln;              // h*64+dh
                int bh = ((grow0 >> 11) << 4) + (gcol >> 6);
                ushort4 st;
                st.x = f2bf(acc[rb][nb][0]); st.y = f2bf(acc[rb][nb][1]);
                st.z = f2bf(acc[rb][nb][2]); st.w = f2bf(acc[rb][nb][3]);
                *(ushort4*)(vt + ((size_t)bh * DHEAD + (gcol & 63)) * SEQ
                                 + (grow0 & (SEQ - 1))) = st;
            }
    }
}

// =====================================================================
// MFMA flash attention, 32x32x16, transpose-free P. 512 blocks, 256 thr.
// Block = 128 q x full keys; wave w owns q [row0+32w, +32).
// S^T = K Q^T (C: col=q=lane&31, row=key=(reg&3)+8*(reg>>2)+4*(lane>>5));
// P^T B-frag built in-register: lane's own C-regs pack into exactly the
// 4 contiguous dwords of B[k=h*8+j] under the induced key permutation;
// V^T A-frag reads the matching permuted keys (two b64 LDS reads).
// exp2-only softmax; truncation-to-bf16 with lsum on truncated values
// (bias cancels in normalization). XCD swizzle: 4 bh per XCD.
// =====================================================================
__global__ __launch_bounds__(256) void attn_kernel(
    const unsigned short* __restrict__ qh, const unsigned short* __restrict__ kh,
    const unsigned short* __restrict__ vt, const unsigned long long* __restrict__ mpack,
    unsigned short* __restrict__ att)
{
    const int t = threadIdx.x, lane = t & 63, w = t >> 6;
    const int h = lane >> 5, lq = lane & 31;

    const int bid = blockIdx.x;
    const int sx = bid >> 3;                    // 0..63
    const int bh = (bid & 7) * 4 + (sx >> 4);   // 4 bh per XCD
    const int qt = sx & 15;
    const int b = bh >> 4, hd = bh & 15;
    const int row0 = qt * 128;
    const int qrow = row0 + w * 32 + lq;

    __shared__ __align__(16) unsigned short SH[128 * 64 + 64 * 128];
    unsigned short* Ks = SH;                // [128 key][64 dh], chunk-swizzled
    unsigned short* Vs = SH + 128 * 64;     // [64 dh][128 key], chunk-swizzled

    const unsigned short* Kb = kh + (size_t)bh * SEQ * DHEAD;
    const unsigned short* Vb = vt + (size_t)bh * DHEAD * SEQ;

    // Q B-frags: B[n=q=lq][k=dh = d*16 + h*8 + j]
    const unsigned short* Qb = qh + ((size_t)bh * SEQ + qrow) * DHEAD;
    bf16x8 qf[4];
    #pragma unroll
    for (int d = 0; d < 4; ++d) qf[d] = *(const bf16x8*)(Qb + d * 16 + h * 8);

    const unsigned long long* Mb = mpack + ((size_t)b * SEQ + qrow) * (SEQ / 64);

    f32x16 acc[2] = {};
    float lsum = 0.f;

    for (int kt = 0; kt < SEQ; kt += 128) {
        __syncthreads();
        #pragma unroll
        for (int i = 0; i < 4; ++i) {
            int s = i * 256 + t;
            int n = s >> 3, c = (s & 7) ^ (n & 7);
            gld_lds16(Kb + (size_t)(kt + n) * DHEAD + c * 8, Ks + (size_t)s * 8);
        }
        #pragma unroll
        for (int i = 0; i < 4; ++i) {
            int s = i * 256 + t;
            int n = s >> 4, c = (s & 15) ^ (n & 7);
            gld_lds16(Vb + (size_t)n * SEQ + kt + c * 8, Vs + (size_t)s * 8);
        }
        __syncthreads();

        const ulonglong2 mw = *(const ulonglong2*)(Mb + (kt >> 6));
        const unsigned long long mh0 = mw.x >> (h * 4);
        const unsigned long long mh1 = mw.y >> (h * 4);

        #pragma unroll
        for (int st = 0; st < 4; ++st) {
            // ---- S^T = K Q^T over this 32-key tile ----
            f32x16 S = {};
            #pragma unroll
            for (int d = 0; d < 4; ++d) {
                bf16x8 kf = *(const bf16x8*)(Ks + (32 * st + lq) * 64
                                             + (((d * 2 + h) ^ (lq & 7)) * 8));
                S = __builtin_amdgcn_mfma_f32_32x32x16_bf16(kf, qf[d], S, 0, 0, 0);
            }
            // ---- mask + exp2 + truncate-pack (lsum on truncated values) ----
            const unsigned long long mh = (st < 2) ? mh0 : mh1;
            const int sb = 32 * (st & 1);
            unsigned int pd[8];
            #pragma unroll
            for (int bb = 0; bb < 4; ++bb) {
                float e[4];
                #pragma unroll
                for (int r = 0; r < 4; ++r) {
                    const bool m = (mh >> (sb + 8 * bb + r)) & 1ull;
                    e[r] = m ? 0.0f : exp2f(S[bb * 4 + r]);
                }
                unsigned int t0 = __float_as_uint(e[0]) & 0xffff0000u;
                unsigned int t1 = __float_as_uint(e[1]) & 0xffff0000u;
                unsigned int t2 = __float_as_uint(e[2]) & 0xffff0000u;
                unsigned int t3 = __float_as_uint(e[3]) & 0xffff0000u;
                lsum += __uint_as_float(t0) + __uint_as_float(t1)
                      + __uint_as_float(t2) + __uint_as_float(t3);
                pd[bb * 2 + 0] = (t0 >> 16) | t1;
                pd[bb * 2 + 1] = (t2 >> 16) | t3;
            }
            // ---- O^T += V^T P^T  (P^T B-frag = own regs; V at permuted keys) ----
            #pragma unroll
            for (int k2 = 0; k2 < 2; ++k2) {
                i32x4 pi = { (int)pd[4 * k2 + 0], (int)pd[4 * k2 + 1],
                             (int)pd[4 * k2 + 2], (int)pd[4 * k2 + 3] };
                bf16x8 pf = __builtin_bit_cast(bf16x8, pi);
                const int g0 = 4 * st + 2 * k2;          // even chunk
                #pragma unroll
                for (int dt = 0; dt < 2; ++dt) {
                    const int vrow = dt * 32 + lq;
                    const unsigned short* vb = Vs + vrow * 128 + 4 * h;
                    bf16x4 v0 = *(const bf16x4*)(vb + ((g0 ^ (lq & 7)) * 8));
                    bf16x4 v1 = *(const bf16x4*)(vb + (((g0 + 1) ^ (lq & 7)) * 8));
                    bf16x8 vf = __builtin_shufflevector(v0, v1, 0, 1, 2, 3, 4, 5, 6, 7);
                    acc[dt] = __builtin_amdgcn_mfma_f32_32x32x16_bf16(vf, pf, acc[dt], 0, 0, 0);
                }
            }
        }
    }

    // ---- epilogue: l-reduce, normalize, LDS transpose, coalesced store ----
    lsum += __shfl_xor(lsum, 32, 64);
    const float inv = 1.0f / lsum;

    __syncthreads();
    unsigned short* Ot = SH;   // [128 q][72]
    #pragma unroll
    for (int dt = 0; dt < 2; ++dt)
        #pragma unroll
        for (int i = 0; i < 16; i += 2) {
            const int dh = dt * 32 + (i & 3) + 8 * (i >> 2) + 4 * h;
            *(unsigned int*)(Ot + (size_t)(w * 32 + lq) * 72 + dh)
                = pk2(acc[dt][i] * inv, acc[dt][i + 1] * inv);
        }
    __syncthreads();
    {
        const int q = t >> 1, half = t & 1;
        const unsigned short* src = Ot + (size_t)q * 72 + half * 32;
        uint4 c0 = *(const uint4*)(src);
        uint4 c1 = *(const uint4*)(src + 8);
        uint4 c2 = *(const uint4*)(src + 16);
        uint4 c3 = *(const uint4*)(src + 24);
        unsigned short* dst = att + ((size_t)b * SEQ + row0 + q) * DMODEL
                                  + hd * DHEAD + half * 32;
        *(uint4*)(dst)      = c0;
        *(uint4*)(dst + 8)  = c1;
        *(uint4*)(dst + 16) = c2;
        *(uint4*)(dst + 24) = c3;
    }
}

// =====================================================================
// Output GEMM: out = att(bf16) @ Wot^T, f32 out. 128x128 tile, BK=64.
// 256 blocks, XCD-swizzled (4 m-tiles per XCD).
// =====================================================================
__global__ __launch_bounds__(256) void out_gemm_kernel(
    const unsigned short* __restrict__ A, const unsigned short* __restrict__ Bt,
    float* __restrict__ C)
{
    const int bid = blockIdx.x;
    const int sx = bid >> 3;                     // 0..31
    const int m0 = ((bid & 7) * 4 + (sx >> 3)) * 128;
    const int n0 = (sx & 7) * 128;

    const int t = threadIdx.x, lane = t & 63, w = t >> 6;
    const int lg = lane >> 4, ln = lane & 15;
    const int wx = w & 1, wy = w >> 1;

    __shared__ __align__(16) unsigned short As[128 * 64];
    __shared__ __align__(16) unsigned short Bs[128 * 64];

    f32x4 acc[4][4] = {};

    for (int kk = 0; kk < DMODEL; kk += 64) {
        #pragma unroll
        for (int i = 0; i < 4; ++i) {
            int s = (w * 4 + i) * 64 + lane;
            int n = s >> 3, c = (s & 7) ^ (n & 7);
            gld_lds16(Bt + (size_t)(n0 + n) * DMODEL + kk + c * 8, Bs + (size_t)s * 8);
        }
        #pragma unroll
        for (int i = 0; i < 4; ++i) {
            int s = (w * 4 + i) * 64 + lane;
            int n = s >> 3, c = (s & 7) ^ (n & 7);
            gld_lds16(A + (size_t)(m0 + n) * DMODEL + kk + c * 8, As + (size_t)s * 8);
        }
        __syncthreads();
        #pragma unroll
        for (int ks = 0; ks < 2; ++ks) {
            bf16x8 af[4], bf[4];
            #pragma unroll
            for (int rb = 0; rb < 4; ++rb) {
                int r = wy * 64 + rb * 16 + ln;
                af[rb] = *(const bf16x8*)(As + r * 64 + (((ks * 4 + lg) ^ (r & 7)) * 8));
            }
            #pragma unroll
            for (int nb = 0; nb < 4; ++nb) {
                int n = wx * 64 + nb * 16 + ln;
                bf[nb] = *(const bf16x8*)(Bs + n * 64 + (((ks * 4 + lg) ^ (n & 7)) * 8));
            }
            #pragma unroll
            for (int rb = 0; rb < 4; ++rb)
                #pragma unroll
                for (int nb = 0; nb < 4; ++nb)
                    acc[rb][nb] = __builtin_amdgcn_mfma_f32_16x16x32_bf16(
                        af[rb], bf[nb], acc[rb][nb], 0, 0, 0);
        }
        __syncthreads();
    }

    #pragma unroll
    for (int rb = 0; rb < 4; ++rb)
        #pragma unroll
        for (int nb = 0; nb < 4; ++nb)
            #pragma unroll
            for (int r = 0; r < 4; ++r) {
                int grow = m0 + wy * 64 + rb * 16 + lg * 4 + r;
                int gcol = n0 + wx * 64 + nb * 16 + ln;
                C[(size_t)grow * DMODEL + gcol] = acc[rb][nb][r];
            }
}

extern "C" void kernel_launch(void* const* d_in, const int* in_sizes, int n_in,
                              void* d_out, int out_size, void* d_ws, size_t ws_size,
                              hipStream_t stream) {
    const float* q    = (const float*)d_in[0];
    const float* k    = (const float*)d_in[1];
    const float* v    = (const float*)d_in[2];
    const int*   mask = (const int*)  d_in[3];
    const float* Wq   = (const float*)d_in[4];
    const float* Wk   = (const float*)d_in[5];
    const float* Wv   = (const float*)d_in[6];
    const float* Wo   = (const float*)d_in[7];
    float* out = (float*)d_out;

    unsigned short* ws  = (unsigned short*)d_ws;
    const size_t n1 = (size_t)NB * NH * SEQ * DHEAD;      // 4,194,304
    const size_t nw = (size_t)NH * DHEAD * DMODEL;        // 1,048,576
    unsigned short* qh  = ws;
    unsigned short* kh  = qh + n1;
    unsigned short* vt  = kh + n1;                        // [bh][dh][seq]
    unsigned short* att = vt + n1;
    unsigned short* Wqt = att + n1;
    unsigned short* Wkt = Wqt + nw;
    unsigned short* Wvt = Wkt + nw;
    unsigned short* Wot = Wvt + nw;
    unsigned long long* mpack = (unsigned long long*)(Wot + (size_t)DMODEL * DMODEL);

    pack_mask_kernel<<<dim3(NB * SEQ / 4), 256, 0, stream>>>(mask, mpack);
    transpose_qkv_kernel<<<dim3(16, 48), 256, 0, stream>>>(Wq, Wk, Wv, Wqt, Wkt, Wvt);
    transpose_wo_kernel<<<dim3(16, 16), 256, 0, stream>>>(Wo, Wot);

    proj_gemm_kernel<<<dim3(768), 256, 0, stream>>>(q, k, v, Wqt, Wkt, Wvt, qh, kh, vt);
    attn_kernel<<<dim3(512), 256, 0, stream>>>(qh, kh, vt, mpack, att);
    out_gemm_kernel<<<dim3(256), 256, 0, stream>>>(att, Wot, out);
}

// Round 6
// 332.061 us; speedup vs baseline: 1.0585x; 1.0585x over previous
//
#include <hip/hip_runtime.h>

#define NB 2
#define NH 16
#define SEQ 2048
#define DMODEL 1024
#define DHEAD 64
// 0.125 (1/sqrt(DH)) / ln(2): folded into Wq so softmax is a bare exp2
#define QSCALE 0.18033688f

typedef __attribute__((ext_vector_type(8))) short bf16x8;
typedef __attribute__((ext_vector_type(4))) short bf16x4;
typedef __attribute__((ext_vector_type(4))) float f32x4;
typedef __attribute__((ext_vector_type(16))) float f32x16;
typedef __attribute__((ext_vector_type(4))) int i32x4;

static __device__ __forceinline__ unsigned short f2bf(float f) {
    unsigned int u = __float_as_uint(f);
    u += 0x7fffu + ((u >> 16) & 1u);   // RNE
    return (unsigned short)(u >> 16);
}
static __device__ __forceinline__ unsigned int pk2(float lo, float hi) {
    return (unsigned int)f2bf(lo) | ((unsigned int)f2bf(hi) << 16);
}
static __device__ __forceinline__ void gld_lds16(const unsigned short* g, unsigned short* l) {
    __builtin_amdgcn_global_load_lds(
        (const __attribute__((address_space(1))) unsigned int*)g,
        (__attribute__((address_space(3))) unsigned int*)l, 16, 0, 0);
}

// =====================================================================
// Prep A: pack bool mask (int32) into u64 bitmask words per (b,s) row.
// =====================================================================
__global__ __launch_bounds__(256) void pack_mask_kernel(
    const int* __restrict__ mask, unsigned long long* __restrict__ mpack)
{
    const int wave = blockIdx.x * 4 + (threadIdx.x >> 6);
    const int lane = threadIdx.x & 63;
    const int* row = mask + (size_t)wave * SEQ;
    unsigned long long* orow = mpack + (size_t)wave * (SEQ / 64);
    for (int w = 0; w < SEQ / 64; ++w) {
        int m = row[w * 64 + lane];
        unsigned long long bits = __ballot(m != 0);
        if (lane == 0) orow[w] = bits;
    }
}

// =====================================================================
// Prep B1: fused Wq/Wk/Wv transpose+cvt (per head 1024x64 -> 64x1024).
// Wq additionally scaled by QSCALE. grid (16, 48).
// =====================================================================
__global__ __launch_bounds__(256) void transpose_qkv_kernel(
    const float* __restrict__ Wq, const float* __restrict__ Wk, const float* __restrict__ Wv,
    unsigned short* __restrict__ Wqt, unsigned short* __restrict__ Wkt, unsigned short* __restrict__ Wvt)
{
    const int z = blockIdx.y, sel = z >> 4, h = z & 15;
    const float* S = (sel == 0 ? Wq : sel == 1 ? Wk : Wv) + (size_t)h * DMODEL * DHEAD;
    unsigned short* D = (sel == 0 ? Wqt : sel == 1 ? Wkt : Wvt) + (size_t)h * DMODEL * DHEAD;
    const float scale = (sel == 0) ? QSCALE : 1.0f;
    const int tile_r = blockIdx.x * 64;
    __shared__ float Ls[64][65];
    const int t = threadIdx.x;
    const int c4 = (t & 15) * 4;
    for (int rr = t >> 4; rr < 64; rr += 16) {
        float4 v = *(const float4*)(S + (size_t)(tile_r + rr) * DHEAD + c4);
        Ls[rr][c4 + 0] = v.x; Ls[rr][c4 + 1] = v.y;
        Ls[rr][c4 + 2] = v.z; Ls[rr][c4 + 3] = v.w;
    }
    __syncthreads();
    const int r4 = (t & 15) * 4;
    for (int cc = t >> 4; cc < 64; cc += 16) {
        ushort4 o;
        o.x = f2bf(Ls[r4 + 0][cc] * scale); o.y = f2bf(Ls[r4 + 1][cc] * scale);
        o.z = f2bf(Ls[r4 + 2][cc] * scale); o.w = f2bf(Ls[r4 + 3][cc] * scale);
        *(ushort4*)(D + (size_t)cc * DMODEL + tile_r + r4) = o;
    }
}

// =====================================================================
// Prep B2: Wo transpose+cvt (1024x1024). grid (16, 16).
// =====================================================================
__global__ __launch_bounds__(256) void transpose_wo_kernel(
    const float* __restrict__ src, unsigned short* __restrict__ dst)
{
    const int tile_c = blockIdx.x * 64, tile_r = blockIdx.y * 64;
    __shared__ float Ls[64][65];
    const int t = threadIdx.x;
    const int c4 = (t & 15) * 4;
    for (int rr = t >> 4; rr < 64; rr += 16) {
        float4 v = *(const float4*)(src + (size_t)(tile_r + rr) * DMODEL + tile_c + c4);
        Ls[rr][c4 + 0] = v.x; Ls[rr][c4 + 1] = v.y;
        Ls[rr][c4 + 2] = v.z; Ls[rr][c4 + 3] = v.w;
    }
    __syncthreads();
    const int r4 = (t & 15) * 4;
    for (int cc = t >> 4; cc < 64; cc += 16) {
        ushort4 o;
        o.x = f2bf(Ls[r4 + 0][cc]); o.y = f2bf(Ls[r4 + 1][cc]);
        o.z = f2bf(Ls[r4 + 2][cc]); o.w = f2bf(Ls[r4 + 3][cc]);
        *(ushort4*)(dst + (size_t)(tile_c + cc) * DMODEL + tile_r + r4) = o;
    }
}

// =====================================================================
// Prep C: q/k/v f32 -> bf16 (roofline copy). grid 6144 (2048 per array).
// =====================================================================
__global__ __launch_bounds__(256) void cvt_qkv_kernel(
    const float* __restrict__ q, const float* __restrict__ k, const float* __restrict__ v,
    unsigned short* __restrict__ qb, unsigned short* __restrict__ kb,
    unsigned short* __restrict__ vb)
{
    const int bid = blockIdx.x;
    const int z = bid >> 11;
    const float* S = (z == 0) ? q : (z == 1) ? k : v;
    unsigned short* D = (z == 0) ? qb : (z == 1) ? kb : vb;
    const size_t i = ((size_t)(bid & 2047) * 256 + threadIdx.x) * 8;
    float4 x0 = *(const float4*)(S + i);
    float4 x1 = *(const float4*)(S + i + 4);
    uint4 val;
    val.x = pk2(x0.x, x0.y); val.y = pk2(x0.z, x0.w);
    val.z = pk2(x1.x, x1.y); val.w = pk2(x1.z, x1.w);
    *(uint4*)(D + i) = val;
}

// =====================================================================
// Fused projection GEMM (pure bf16, gld_lds both tiles). 768 blocks,
// XCD-swizzled: xcd=bid&7 owns 12 m-tiles, n fastest for A L2 reuse.
// z<2 -> qh/kh [bh][s][dh]; z=2 -> vt transposed [bh][dh][seq].
// =====================================================================
__global__ __launch_bounds__(256) void proj_gemm_kernel(
    const unsigned short* __restrict__ qb, const unsigned short* __restrict__ kb,
    const unsigned short* __restrict__ vb,
    const unsigned short* __restrict__ Wqt, const unsigned short* __restrict__ Wkt,
    const unsigned short* __restrict__ Wvt,
    unsigned short* __restrict__ qh, unsigned short* __restrict__ kh,
    unsigned short* __restrict__ vt)
{
    const int bid = blockIdx.x;
    const int sx = bid >> 3;                       // 0..95
    const int mtg = (bid & 7) * 12 + (sx >> 3);    // 0..95 global m-tile
    const int z = mtg >> 5;                        // 0..2
    const int m0 = (mtg & 31) * 128;
    const int n0 = (sx & 7) * 128;

    const unsigned short* A = (z == 0) ? qb : (z == 1) ? kb : vb;
    const unsigned short* Bt = (z == 0) ? Wqt : (z == 1) ? Wkt : Wvt;

    const int t = threadIdx.x, lane = t & 63, w = t >> 6;
    const int lg = lane >> 4, ln = lane & 15;
    const int wx = w & 1, wy = w >> 1;

    __shared__ __align__(16) unsigned short As[128 * 64];
    __shared__ __align__(16) unsigned short Bs[128 * 64];

    f32x4 acc[4][4] = {};

    for (int kk = 0; kk < DMODEL; kk += 64) {
        #pragma unroll
        for (int i = 0; i < 4; ++i) {
            int s = (w * 4 + i) * 64 + lane;
            int n = s >> 3, c = (s & 7) ^ (n & 7);
            gld_lds16(Bt + (size_t)(n0 + n) * DMODEL + kk + c * 8, Bs + (size_t)s * 8);
        }
        #pragma unroll
        for (int i = 0; i < 4; ++i) {
            int s = (w * 4 + i) * 64 + lane;
            int n = s >> 3, c = (s & 7) ^ (n & 7);
            gld_lds16(A + (size_t)(m0 + n) * DMODEL + kk + c * 8, As + (size_t)s * 8);
        }
        __syncthreads();
        #pragma unroll
        for (int ks = 0; ks < 2; ++ks) {
            bf16x8 af[4], bf[4];
            #pragma unroll
            for (int rb = 0; rb < 4; ++rb) {
                int r = wy * 64 + rb * 16 + ln;
                af[rb] = *(const bf16x8*)(As + r * 64 + (((ks * 4 + lg) ^ (r & 7)) * 8));
            }
            #pragma unroll
            for (int nb = 0; nb < 4; ++nb) {
                int n = wx * 64 + nb * 16 + ln;
                bf[nb] = *(const bf16x8*)(Bs + n * 64 + (((ks * 4 + lg) ^ (n & 7)) * 8));
            }
            #pragma unroll
            for (int rb = 0; rb < 4; ++rb)
                #pragma unroll
                for (int nb = 0; nb < 4; ++nb)
                    acc[rb][nb] = __builtin_amdgcn_mfma_f32_16x16x32_bf16(
                        af[rb], bf[nb], acc[rb][nb], 0, 0, 0);
        }
        __syncthreads();
    }

    if (z < 2) {
        unsigned short* Y = (z == 0) ? qh : kh;   // [bh][s][dh]
        #pragma unroll
        for (int rb = 0; rb < 4; ++rb)
            #pragma unroll
            for (int nb = 0; nb < 4; ++nb)
                #pragma unroll
                for (int r = 0; r < 4; ++r) {
                    int grow = m0 + wy * 64 + rb * 16 + lg * 4 + r;   // b*2048+s
                    int gcol = n0 + wx * 64 + nb * 16 + ln;           // h*64+e
                    size_t idx = ((size_t)((grow >> 11) * NH + (gcol >> 6)) * SEQ
                                  + (grow & (SEQ - 1))) * DHEAD + (gcol & 63);
                    Y[idx] = f2bf(acc[rb][nb][r]);
                }
    } else {
        // V transposed: vt[bh][dh][seq]
        #pragma unroll
        for (int rb = 0; rb < 4; ++rb)
            #pragma unroll
            for (int nb = 0; nb < 4; ++nb) {
                int grow0 = m0 + wy * 64 + rb * 16 + lg * 4;          // b*2048+s (s%4==0)
                int gcol  = n0 + wx * 64 + nb * 16 + ln;              // h*64+dh
                int bh = ((grow0 >> 11) << 4) + (gcol >> 6);
                ushort4 st;
                st.x = f2bf(acc[rb][nb][0]); st.y = f2bf(acc[rb][nb][1]);
                st.z = f2bf(acc[rb][nb][2]); st.w = f2bf(acc[rb][nb][3]);
                *(ushort4*)(vt + ((size_t)bh * DHEAD + (gcol & 63)) * SEQ
                                 + (grow0 & (SEQ - 1))) = st;
            }
    }
}

// =====================================================================
// MFMA flash attention, 32x32x16, K-split x2. 1024 blocks, 256 thr.
// Block = (bh, 128-q tile, key half); wave w owns q [row0+32w, +32).
// No-max exp2 softmax => halves combine by simple addition.
// Partials: Opart[half][bh][dh][q] f32, Lpart[half][bh][q] f32.
// =====================================================================
__global__ __launch_bounds__(256, 4) void attn_kernel(
    const unsigned short* __restrict__ qh, const unsigned short* __restrict__ kh,
    const unsigned short* __restrict__ vt, const unsigned long long* __restrict__ mpack,
    float* __restrict__ Opart, float* __restrict__ Lpart)
{
    const int t = threadIdx.x, lane = t & 63, w = t >> 6;
    const int h = lane >> 5, lq = lane & 31;
    const int L = lq & 7;

    const int bid = blockIdx.x;
    const int r_ = bid >> 3;                     // 0..127
    const int bh = (bid & 7) * 4 + (r_ >> 5);    // 4 bh per XCD
    const int r2 = r_ & 31;
    const int qt = r2 >> 1, half = r2 & 1;
    const int b = bh >> 4;
    const int row0 = qt * 128;
    const int qrow = row0 + w * 32 + lq;
    const int kt0 = half * (SEQ / 2);

    __shared__ __align__(16) unsigned short Ks[128 * 64];    // [key][dh], swizzled
    __shared__ __align__(16) unsigned short Vs[64 * 128];    // [dh][key], swizzled

    const unsigned short* Kb = kh + (size_t)bh * SEQ * DHEAD;
    const unsigned short* Vb = vt + (size_t)bh * DHEAD * SEQ;

    // Q B-frags: B[n=q=lq][k=dh = d*16 + h*8 + j]
    const unsigned short* Qb = qh + ((size_t)bh * SEQ + qrow) * DHEAD;
    bf16x8 qf[4];
    #pragma unroll
    for (int d = 0; d < 4; ++d) qf[d] = *(const bf16x8*)(Qb + d * 16 + h * 8);

    // hoisted LDS fragment base pointers (per-iteration offsets are immediates)
    const unsigned short* kbase[4];
    #pragma unroll
    for (int d = 0; d < 4; ++d)
        kbase[d] = Ks + lq * 64 + (((d * 2 + h) ^ L) * 8);
    const unsigned short* vbase[2];
    #pragma unroll
    for (int dt = 0; dt < 2; ++dt)
        vbase[dt] = Vs + (dt * 32 + lq) * 128 + 4 * h;

    const unsigned long long* Mb = mpack + ((size_t)b * SEQ + qrow) * (SEQ / 64);

    f32x16 acc[2] = {};
    float lsum = 0.f;

    for (int kt = kt0; kt < kt0 + SEQ / 2; kt += 128) {
        __syncthreads();
        #pragma unroll
        for (int i = 0; i < 4; ++i) {
            int s = i * 256 + t;
            int n = s >> 3, c = (s & 7) ^ (n & 7);
            gld_lds16(Kb + (size_t)(kt + n) * DHEAD + c * 8, Ks + (size_t)s * 8);
        }
        #pragma unroll
        for (int i = 0; i < 4; ++i) {
            int s = i * 256 + t;
            int n = s >> 4, c = (s & 15) ^ (n & 7);
            gld_lds16(Vb + (size_t)n * SEQ + kt + c * 8, Vs + (size_t)s * 8);
        }
        __syncthreads();

        const ulonglong2 mw = *(const ulonglong2*)(Mb + (kt >> 6));
        const unsigned long long mh0 = mw.x >> (h * 4);
        const unsigned long long mh1 = mw.y >> (h * 4);

        #pragma unroll
        for (int st = 0; st < 4; ++st) {
            // ---- S^T = K Q^T over this 32-key tile ----
            f32x16 S = {};
            #pragma unroll
            for (int d = 0; d < 4; ++d) {
                bf16x8 kf = *(const bf16x8*)(kbase[d] + st * 32 * 64);
                S = __builtin_amdgcn_mfma_f32_32x32x16_bf16(kf, qf[d], S, 0, 0, 0);
            }
            // ---- mask + raw exp2 + perm-pack (lsum on truncated values) ----
            const unsigned long long mh = (st < 2) ? mh0 : mh1;
            const int sb = 32 * (st & 1);
            unsigned int pd[8];
            #pragma unroll
            for (int bb = 0; bb < 4; ++bb) {
                float e[4];
                #pragma unroll
                for (int rr = 0; rr < 4; ++rr) {
                    const bool m = (mh >> (sb + 8 * bb + rr)) & 1ull;
                    float ex = __builtin_amdgcn_exp2f(S[bb * 4 + rr]);
                    e[rr] = m ? 0.0f : ex;
                }
                unsigned int t01 = __builtin_amdgcn_perm(
                    __float_as_uint(e[1]), __float_as_uint(e[0]), 0x07060302u);
                unsigned int t23 = __builtin_amdgcn_perm(
                    __float_as_uint(e[3]), __float_as_uint(e[2]), 0x07060302u);
                lsum += __uint_as_float(t01 << 16);
                lsum += __uint_as_float(t01 & 0xffff0000u);
                lsum += __uint_as_float(t23 << 16);
                lsum += __uint_as_float(t23 & 0xffff0000u);
                pd[bb * 2 + 0] = t01;
                pd[bb * 2 + 1] = t23;
            }
            // ---- O^T += V^T P^T (P^T B-frag = own regs; V at permuted keys) ----
            #pragma unroll
            for (int k2 = 0; k2 < 2; ++k2) {
                i32x4 pi = { (int)pd[4 * k2 + 0], (int)pd[4 * k2 + 1],
                             (int)pd[4 * k2 + 2], (int)pd[4 * k2 + 3] };
                bf16x8 pf = __builtin_bit_cast(bf16x8, pi);
                const int p0 = ((4 * st + 2 * k2) ^ L) * 8;
                #pragma unroll
                for (int dt = 0; dt < 2; ++dt) {
                    bf16x4 v0 = *(const bf16x4*)(vbase[dt] + p0);
                    bf16x4 v1 = *(const bf16x4*)(vbase[dt] + (p0 ^ 8));
                    bf16x8 vf = __builtin_shufflevector(v0, v1, 0, 1, 2, 3, 4, 5, 6, 7);
                    acc[dt] = __builtin_amdgcn_mfma_f32_32x32x16_bf16(vf, pf, acc[dt], 0, 0, 0);
                }
            }
        }
    }

    // ---- epilogue: store f32 partials (coalesced along q) ----
    lsum += __shfl_xor(lsum, 32, 64);
    float* Op = Opart + (size_t)((half << 5) | bh) * DHEAD * SEQ;
    #pragma unroll
    for (int dt = 0; dt < 2; ++dt)
        #pragma unroll
        for (int i = 0; i < 16; ++i) {
            const int dh = dt * 32 + (i & 3) + 8 * (i >> 2) + 4 * h;
            Op[(size_t)dh * SEQ + qrow] = acc[dt][i];
        }
    if (h == 0)
        Lpart[(size_t)((half << 5) | bh) * SEQ + qrow] = lsum;
}

// =====================================================================
// Combine: att[b][s][hd*64+dh] = (O0+O1)/(l0+l1), bf16. grid 512.
// =====================================================================
__global__ __launch_bounds__(256) void combine_kernel(
    const float* __restrict__ Opart, const float* __restrict__ Lpart,
    unsigned short* __restrict__ att)
{
    const int bid = blockIdx.x;
    const int bh = bid >> 4, qt = bid & 15;
    const int b = bh >> 4, hd = bh & 15;
    const int row0 = qt * 128;
    const int t = threadIdx.x;

    __shared__ float linv[128];
    __shared__ unsigned short Ot[128][68];

    if (t < 128) {
        float l = Lpart[(size_t)bh * SEQ + row0 + t]
                + Lpart[(size_t)(32 + bh) * SEQ + row0 + t];
        linv[t] = 1.0f / l;
    }
    __syncthreads();

    const int dh = t >> 2, qg = (t & 3) * 32;
    const float* p0 = Opart + ((size_t)bh * DHEAD + dh) * SEQ + row0 + qg;
    const float* p1 = Opart + ((size_t)(32 + bh) * DHEAD + dh) * SEQ + row0 + qg;
    #pragma unroll
    for (int j = 0; j < 8; ++j) {
        float4 a = *(const float4*)(p0 + j * 4);
        float4 c = *(const float4*)(p1 + j * 4);
        const int q = qg + j * 4;
        Ot[q + 0][dh] = f2bf((a.x + c.x) * linv[q + 0]);
        Ot[q + 1][dh] = f2bf((a.y + c.y) * linv[q + 1]);
        Ot[q + 2][dh] = f2bf((a.z + c.z) * linv[q + 2]);
        Ot[q + 3][dh] = f2bf((a.w + c.w) * linv[q + 3]);
    }
    __syncthreads();
    {
        const int q = t >> 1, hf = t & 1;
        const unsigned short* src = &Ot[q][hf * 32];
        unsigned short* dst = att + ((size_t)b * SEQ + row0 + q) * DMODEL
                                  + hd * DHEAD + hf * 32;
        #pragma unroll
        for (int i = 0; i < 8; ++i)
            *(ushort4*)(dst + i * 4) = *(const ushort4*)(src + i * 4);
    }
}

// =====================================================================
// Output GEMM: out = att(bf16) @ Wot^T, f32 out. 128x128 tile, BK=64.
// 256 blocks, XCD-swizzled (4 m-tiles per XCD).
// =====================================================================
__global__ __launch_bounds__(256) void out_gemm_kernel(
    const unsigned short* __restrict__ A, const unsigned short* __restrict__ Bt,
    float* __restrict__ C)
{
    const int bid = blockIdx.x;
    const int sx = bid >> 3;                     // 0..31
    const int m0 = ((bid & 7) * 4 + (sx >> 3)) * 128;
    const int n0 = (sx & 7) * 128;

    const int t = threadIdx.x, lane = t & 63, w = t >> 6;
    const int lg = lane >> 4, ln = lane & 15;
    const int wx = w & 1, wy = w >> 1;

    __shared__ __align__(16) unsigned short As[128 * 64];
    __shared__ __align__(16) unsigned short Bs[128 * 64];

    f32x4 acc[4][4] = {};

    for (int kk = 0; kk < DMODEL; kk += 64) {
        #pragma unroll
        for (int i = 0; i < 4; ++i) {
            int s = (w * 4 + i) * 64 + lane;
            int n = s >> 3, c = (s & 7) ^ (n & 7);
            gld_lds16(Bt + (size_t)(n0 + n) * DMODEL + kk + c * 8, Bs + (size_t)s * 8);
        }
        #pragma unroll
        for (int i = 0; i < 4; ++i) {
            int s = (w * 4 + i) * 64 + lane;
            int n = s >> 3, c = (s & 7) ^ (n & 7);
            gld_lds16(A + (size_t)(m0 + n) * DMODEL + kk + c * 8, As + (size_t)s * 8);
        }
        __syncthreads();
        #pragma unroll
        for (int ks = 0; ks < 2; ++ks) {
            bf16x8 af[4], bf[4];
            #pragma unroll
            for (int rb = 0; rb < 4; ++rb) {
                int r = wy * 64 + rb * 16 + ln;
                af[rb] = *(const bf16x8*)(As + r * 64 + (((ks * 4 + lg) ^ (r & 7)) * 8));
            }
            #pragma unroll
            for (int nb = 0; nb < 4; ++nb) {
                int n = wx * 64 + nb * 16 + ln;
                bf[nb] = *(const bf16x8*)(Bs + n * 64 + (((ks * 4 + lg) ^ (n & 7)) * 8));
            }
            #pragma unroll
            for (int rb = 0; rb < 4; ++rb)
                #pragma unroll
                for (int nb = 0; nb < 4; ++nb)
                    acc[rb][nb] = __builtin_amdgcn_mfma_f32_16x16x32_bf16(
                        af[rb], bf[nb], acc[rb][nb], 0, 0, 0);
        }
        __syncthreads();
    }

    #pragma unroll
    for (int rb = 0; rb < 4; ++rb)
        #pragma unroll
        for (int nb = 0; nb < 4; ++nb)
            #pragma unroll
            for (int r = 0; r < 4; ++r) {
                int grow = m0 + wy * 64 + rb * 16 + lg * 4 + r;
                int gcol = n0 + wx * 64 + nb * 16 + ln;
                C[(size_t)grow * DMODEL + gcol] = acc[rb][nb][r];
            }
}

extern "C" void kernel_launch(void* const* d_in, const int* in_sizes, int n_in,
                              void* d_out, int out_size, void* d_ws, size_t ws_size,
                              hipStream_t stream) {
    const float* q    = (const float*)d_in[0];
    const float* k    = (const float*)d_in[1];
    const float* v    = (const float*)d_in[2];
    const int*   mask = (const int*)  d_in[3];
    const float* Wq   = (const float*)d_in[4];
    const float* Wk   = (const float*)d_in[5];
    const float* Wv   = (const float*)d_in[6];
    const float* Wo   = (const float*)d_in[7];
    float* out = (float*)d_out;

    unsigned short* ws  = (unsigned short*)d_ws;
    const size_t n1 = (size_t)NB * NH * SEQ * DHEAD;      // 4,194,304 shorts
    const size_t nw = (size_t)NH * DHEAD * DMODEL;        // 1,048,576 shorts
    unsigned short* qh  = ws;                             // [0, n1)
    unsigned short* kh  = qh + n1;
    unsigned short* vt  = kh + n1;                        // [bh][dh][seq]
    unsigned short* att = vt + n1;
    unsigned short* Wqt = att + n1;                       // 4*nw == n1 total
    unsigned short* Wkt = Wqt + nw;
    unsigned short* Wvt = Wkt + nw;
    unsigned short* Wot = Wvt + nw;
    unsigned long long* mpack = (unsigned long long*)(Wot + nw);   // 1 MB
    // region A (aliased): qb/kb/vb (proj phase) then Opart/Lpart (attn phase)
    unsigned short* regA = (unsigned short*)(mpack + (size_t)NB * SEQ * (SEQ / 64));
    unsigned short* qb = regA;
    unsigned short* kb = qb + n1;
    unsigned short* vb = kb + n1;
    float* Opart = (float*)regA;                          // 2*32*64*2048 f32 = 33.5 MB
    float* Lpart = Opart + (size_t)2 * 32 * DHEAD * SEQ;  // 0.5 MB

    pack_mask_kernel<<<dim3(NB * SEQ / 4), 256, 0, stream>>>(mask, mpack);
    transpose_qkv_kernel<<<dim3(16, 48), 256, 0, stream>>>(Wq, Wk, Wv, Wqt, Wkt, Wvt);
    transpose_wo_kernel<<<dim3(16, 16), 256, 0, stream>>>(Wo, Wot);
    cvt_qkv_kernel<<<dim3(6144), 256, 0, stream>>>(q, k, v, qb, kb, vb);

    proj_gemm_kernel<<<dim3(768), 256, 0, stream>>>(qb, kb, vb, Wqt, Wkt, Wvt, qh, kh, vt);
    attn_kernel<<<dim3(1024), 256, 0, stream>>>(qh, kh, vt, mpack, Opart, Lpart);
    combine_kernel<<<dim3(512), 256, 0, stream>>>(Opart, Lpart, att);
    out_gemm_kernel<<<dim3(256), 256, 0, stream>>>(att, Wot, out);
}

// Round 7
// 303.750 us; speedup vs baseline: 1.1572x; 1.0932x over previous
//
#include <hip/hip_runtime.h>

#define NB 2
#define NH 16
#define SEQ 2048
#define DMODEL 1024
#define DHEAD 64
// 0.125 (1/sqrt(DH)) / ln(2): folded into Wq so softmax is a bare exp2
#define QSCALE 0.18033688f

typedef __attribute__((ext_vector_type(8))) short bf16x8;
typedef __attribute__((ext_vector_type(4))) short bf16x4;
typedef __attribute__((ext_vector_type(4))) float f32x4;
typedef __attribute__((ext_vector_type(16))) float f32x16;
typedef __attribute__((ext_vector_type(4))) int i32x4;

static __device__ __forceinline__ unsigned short f2bf(float f) {
    unsigned int u = __float_as_uint(f);
    u += 0x7fffu + ((u >> 16) & 1u);   // RNE
    return (unsigned short)(u >> 16);
}
static __device__ __forceinline__ unsigned int pk2(float lo, float hi) {
    return (unsigned int)f2bf(lo) | ((unsigned int)f2bf(hi) << 16);
}
static __device__ __forceinline__ void gld_lds16(const unsigned short* g, unsigned short* l) {
    __builtin_amdgcn_global_load_lds(
        (const __attribute__((address_space(1))) unsigned int*)g,
        (__attribute__((address_space(3))) unsigned int*)l, 16, 0, 0);
}

// =====================================================================
// Fused prep (one dispatch, 8192 blocks):
//  [0,1024)     pack mask -> u64 bit words
//  [1024,1792)  Wq/Wk/Wv transpose+cvt (Wq scaled)
//  [1792,2048)  Wo transpose+cvt
//  [2048,8192)  q/k/v f32->bf16 copy
// =====================================================================
__global__ __launch_bounds__(256) void prep_kernel(
    const int* __restrict__ mask, unsigned long long* __restrict__ mpack,
    const float* __restrict__ Wq, const float* __restrict__ Wk, const float* __restrict__ Wv,
    unsigned short* __restrict__ Wqt, unsigned short* __restrict__ Wkt,
    unsigned short* __restrict__ Wvt,
    const float* __restrict__ Wo, unsigned short* __restrict__ Wot,
    const float* __restrict__ q, const float* __restrict__ k, const float* __restrict__ v,
    unsigned short* __restrict__ qb, unsigned short* __restrict__ kb,
    unsigned short* __restrict__ vb)
{
    __shared__ __align__(16) float Ls[64][65];
    const int bid = blockIdx.x, t = threadIdx.x;

    if (bid < 1024) {
        // ---- mask pack ----
        const int wave = bid * 4 + (t >> 6);
        const int lane = t & 63;
        const int* row = mask + (size_t)wave * SEQ;
        unsigned long long* orow = mpack + (size_t)wave * (SEQ / 64);
        for (int w = 0; w < SEQ / 64; ++w) {
            int m = row[w * 64 + lane];
            unsigned long long bits = __ballot(m != 0);
            if (lane == 0) orow[w] = bits;
        }
    } else if (bid < 2048) {
        // ---- weight transposes ----
        const float* S; unsigned short* D; float scale; int R, tile_r, tile_c, ostride;
        if (bid < 1792) {
            const int local = bid - 1024, z = local >> 4, sel = z >> 4, h = z & 15;
            S = (sel == 0 ? Wq : sel == 1 ? Wk : Wv) + (size_t)h * DMODEL * DHEAD;
            D = (sel == 0 ? Wqt : sel == 1 ? Wkt : Wvt) + (size_t)h * DMODEL * DHEAD;
            scale = (sel == 0) ? QSCALE : 1.0f;
            tile_r = (local & 15) * 64; tile_c = 0; R = DHEAD; ostride = DMODEL;
        } else {
            const int local = bid - 1792;
            S = Wo; D = Wot; scale = 1.0f;
            tile_c = (local & 15) * 64; tile_r = (local >> 4) * 64; R = DMODEL; ostride = DMODEL;
        }
        const int c4 = (t & 15) * 4;
        for (int rr = t >> 4; rr < 64; rr += 16) {
            float4 x = *(const float4*)(S + (size_t)(tile_r + rr) * R + tile_c + c4);
            Ls[rr][c4 + 0] = x.x; Ls[rr][c4 + 1] = x.y;
            Ls[rr][c4 + 2] = x.z; Ls[rr][c4 + 3] = x.w;
        }
        __syncthreads();
        const int r4 = (t & 15) * 4;
        for (int cc = t >> 4; cc < 64; cc += 16) {
            ushort4 o;
            o.x = f2bf(Ls[r4 + 0][cc] * scale); o.y = f2bf(Ls[r4 + 1][cc] * scale);
            o.z = f2bf(Ls[r4 + 2][cc] * scale); o.w = f2bf(Ls[r4 + 3][cc] * scale);
            *(ushort4*)(D + (size_t)(tile_c + cc) * ostride + tile_r + r4) = o;
        }
    } else {
        // ---- q/k/v f32 -> bf16 ----
        const int local = bid - 2048;
        const int z = local >> 11;
        const float* S = (z == 0) ? q : (z == 1) ? k : v;
        unsigned short* D = (z == 0) ? qb : (z == 1) ? kb : vb;
        const size_t i = ((size_t)(local & 2047) * 256 + t) * 8;
        float4 x0 = *(const float4*)(S + i);
        float4 x1 = *(const float4*)(S + i + 4);
        uint4 val;
        val.x = pk2(x0.x, x0.y); val.y = pk2(x0.z, x0.w);
        val.z = pk2(x1.x, x1.y); val.w = pk2(x1.z, x1.w);
        *(uint4*)(D + i) = val;
    }
}

// =====================================================================
// Fused projection GEMM (pure bf16, gld_lds both tiles). 768 blocks,
// XCD-swizzled. z<2 -> qh/kh [bh][s][dh]; z=2 -> vt [bh][dh][seq].
// =====================================================================
__global__ __launch_bounds__(256) void proj_gemm_kernel(
    const unsigned short* __restrict__ qb, const unsigned short* __restrict__ kb,
    const unsigned short* __restrict__ vb,
    const unsigned short* __restrict__ Wqt, const unsigned short* __restrict__ Wkt,
    const unsigned short* __restrict__ Wvt,
    unsigned short* __restrict__ qh, unsigned short* __restrict__ kh,
    unsigned short* __restrict__ vt)
{
    const int bid = blockIdx.x;
    const int sx = bid >> 3;
    const int mtg = (bid & 7) * 12 + (sx >> 3);
    const int z = mtg >> 5;
    const int m0 = (mtg & 31) * 128;
    const int n0 = (sx & 7) * 128;

    const unsigned short* A = (z == 0) ? qb : (z == 1) ? kb : vb;
    const unsigned short* Bt = (z == 0) ? Wqt : (z == 1) ? Wkt : Wvt;

    const int t = threadIdx.x, lane = t & 63, w = t >> 6;
    const int lg = lane >> 4, ln = lane & 15;
    const int wx = w & 1, wy = w >> 1;

    __shared__ __align__(16) unsigned short As[128 * 64];
    __shared__ __align__(16) unsigned short Bs[128 * 64];

    f32x4 acc[4][4] = {};

    for (int kk = 0; kk < DMODEL; kk += 64) {
        #pragma unroll
        for (int i = 0; i < 4; ++i) {
            int s = (w * 4 + i) * 64 + lane;
            int n = s >> 3, c = (s & 7) ^ (n & 7);
            gld_lds16(Bt + (size_t)(n0 + n) * DMODEL + kk + c * 8, Bs + (size_t)s * 8);
        }
        #pragma unroll
        for (int i = 0; i < 4; ++i) {
            int s = (w * 4 + i) * 64 + lane;
            int n = s >> 3, c = (s & 7) ^ (n & 7);
            gld_lds16(A + (size_t)(m0 + n) * DMODEL + kk + c * 8, As + (size_t)s * 8);
        }
        __syncthreads();
        #pragma unroll
        for (int ks = 0; ks < 2; ++ks) {
            bf16x8 af[4], bf[4];
            #pragma unroll
            for (int rb = 0; rb < 4; ++rb) {
                int r = wy * 64 + rb * 16 + ln;
                af[rb] = *(const bf16x8*)(As + r * 64 + (((ks * 4 + lg) ^ (r & 7)) * 8));
            }
            #pragma unroll
            for (int nb = 0; nb < 4; ++nb) {
                int n = wx * 64 + nb * 16 + ln;
                bf[nb] = *(const bf16x8*)(Bs + n * 64 + (((ks * 4 + lg) ^ (n & 7)) * 8));
            }
            #pragma unroll
            for (int rb = 0; rb < 4; ++rb)
                #pragma unroll
                for (int nb = 0; nb < 4; ++nb)
                    acc[rb][nb] = __builtin_amdgcn_mfma_f32_16x16x32_bf16(
                        af[rb], bf[nb], acc[rb][nb], 0, 0, 0);
        }
        __syncthreads();
    }

    if (z < 2) {
        unsigned short* Y = (z == 0) ? qh : kh;
        #pragma unroll
        for (int rb = 0; rb < 4; ++rb)
            #pragma unroll
            for (int nb = 0; nb < 4; ++nb)
                #pragma unroll
                for (int r = 0; r < 4; ++r) {
                    int grow = m0 + wy * 64 + rb * 16 + lg * 4 + r;
                    int gcol = n0 + wx * 64 + nb * 16 + ln;
                    size_t idx = ((size_t)((grow >> 11) * NH + (gcol >> 6)) * SEQ
                                  + (grow & (SEQ - 1))) * DHEAD + (gcol & 63);
                    Y[idx] = f2bf(acc[rb][nb][r]);
                }
    } else {
        #pragma unroll
        for (int rb = 0; rb < 4; ++rb)
            #pragma unroll
            for (int nb = 0; nb < 4; ++nb) {
                int grow0 = m0 + wy * 64 + rb * 16 + lg * 4;
                int gcol  = n0 + wx * 64 + nb * 16 + ln;
                int bh = ((grow0 >> 11) << 4) + (gcol >> 6);
                ushort4 st;
                st.x = f2bf(acc[rb][nb][0]); st.y = f2bf(acc[rb][nb][1]);
                st.z = f2bf(acc[rb][nb][2]); st.w = f2bf(acc[rb][nb][3]);
                *(ushort4*)(vt + ((size_t)bh * DHEAD + (gcol & 63)) * SEQ
                                 + (grow0 & (SEQ - 1))) = st;
            }
    }
}

// =====================================================================
// MFMA flash attention, 32x32x16, K-split x2. 1024 blocks, 256 thr.
// bf16 non-temporal partials (bypass L2 so K/V tiles stay resident).
// Conflict-free LDS swizzle: chunk ^ (row&7) ^ ((row>>3)&3).
// =====================================================================
__global__ __launch_bounds__(256, 4) void attn_kernel(
    const unsigned short* __restrict__ qh, const unsigned short* __restrict__ kh,
    const unsigned short* __restrict__ vt, const unsigned long long* __restrict__ mpack,
    unsigned short* __restrict__ Opart, float* __restrict__ Lpart)
{
    const int t = threadIdx.x, lane = t & 63, w = t >> 6;
    const int h = lane >> 5, lq = lane & 31;
    const int L = lq & 7, X = (lq >> 3) & 3;

    const int bid = blockIdx.x;
    const int r_ = bid >> 3;
    const int bh = (bid & 7) * 4 + (r_ >> 5);
    const int r2 = r_ & 31;
    const int qt = r2 >> 1, half = r2 & 1;
    const int b = bh >> 4;
    const int row0 = qt * 128;
    const int qrow = row0 + w * 32 + lq;
    const int kt0 = half * (SEQ / 2);

    __shared__ __align__(16) unsigned short Ks[128 * 64];
    __shared__ __align__(16) unsigned short Vs[64 * 128];

    const unsigned short* Kb = kh + (size_t)bh * SEQ * DHEAD;
    const unsigned short* Vb = vt + (size_t)bh * DHEAD * SEQ;

    const unsigned short* Qb = qh + ((size_t)bh * SEQ + qrow) * DHEAD;
    bf16x8 qf[4];
    #pragma unroll
    for (int d = 0; d < 4; ++d) qf[d] = *(const bf16x8*)(Qb + d * 16 + h * 8);

    const unsigned short* kbase[4];
    #pragma unroll
    for (int d = 0; d < 4; ++d)
        kbase[d] = Ks + lq * 64 + (((d * 2 + h) ^ L ^ X) * 8);
    const unsigned short* vbase[2];
    #pragma unroll
    for (int dt = 0; dt < 2; ++dt)
        vbase[dt] = Vs + (dt * 32 + lq) * 128 + 4 * h;

    const unsigned long long* Mb = mpack + ((size_t)b * SEQ + qrow) * (SEQ / 64);

    f32x16 acc[2] = {};
    float lsum = 0.f;

    for (int kt = kt0; kt < kt0 + SEQ / 2; kt += 128) {
        __syncthreads();
        #pragma unroll
        for (int i = 0; i < 4; ++i) {
            int s = i * 256 + t;
            int n = s >> 3, c = (s & 7) ^ (n & 7) ^ ((n >> 3) & 3);
            gld_lds16(Kb + (size_t)(kt + n) * DHEAD + c * 8, Ks + (size_t)s * 8);
        }
        #pragma unroll
        for (int i = 0; i < 4; ++i) {
            int s = i * 256 + t;
            int n = s >> 4, c = (s & 15) ^ (n & 7) ^ ((n >> 3) & 3);
            gld_lds16(Vb + (size_t)n * SEQ + kt + c * 8, Vs + (size_t)s * 8);
        }
        __syncthreads();

        const ulonglong2 mw = *(const ulonglong2*)(Mb + (kt >> 6));
        const unsigned long long mh0 = mw.x >> (h * 4);
        const unsigned long long mh1 = mw.y >> (h * 4);

        #pragma unroll
        for (int st = 0; st < 4; ++st) {
            f32x16 S = {};
            #pragma unroll
            for (int d = 0; d < 4; ++d) {
                bf16x8 kf = *(const bf16x8*)(kbase[d] + st * 32 * 64);
                S = __builtin_amdgcn_mfma_f32_32x32x16_bf16(kf, qf[d], S, 0, 0, 0);
            }
            const unsigned long long mh = (st < 2) ? mh0 : mh1;
            const int sb = 32 * (st & 1);
            unsigned int pd[8];
            #pragma unroll
            for (int bb = 0; bb < 4; ++bb) {
                float e[4];
                #pragma unroll
                for (int rr = 0; rr < 4; ++rr) {
                    const bool m = (mh >> (sb + 8 * bb + rr)) & 1ull;
                    float ex = __builtin_amdgcn_exp2f(S[bb * 4 + rr]);
                    e[rr] = m ? 0.0f : ex;
                }
                unsigned int t01 = __builtin_amdgcn_perm(
                    __float_as_uint(e[1]), __float_as_uint(e[0]), 0x07060302u);
                unsigned int t23 = __builtin_amdgcn_perm(
                    __float_as_uint(e[3]), __float_as_uint(e[2]), 0x07060302u);
                lsum += __uint_as_float(t01 << 16);
                lsum += __uint_as_float(t01 & 0xffff0000u);
                lsum += __uint_as_float(t23 << 16);
                lsum += __uint_as_float(t23 & 0xffff0000u);
                pd[bb * 2 + 0] = t01;
                pd[bb * 2 + 1] = t23;
            }
            #pragma unroll
            for (int k2 = 0; k2 < 2; ++k2) {
                i32x4 pi = { (int)pd[4 * k2 + 0], (int)pd[4 * k2 + 1],
                             (int)pd[4 * k2 + 2], (int)pd[4 * k2 + 3] };
                bf16x8 pf = __builtin_bit_cast(bf16x8, pi);
                const int p0 = (((4 * st + 2 * k2) ^ L ^ X)) * 8;
                #pragma unroll
                for (int dt = 0; dt < 2; ++dt) {
                    bf16x4 v0 = *(const bf16x4*)(vbase[dt] + p0);
                    bf16x4 v1 = *(const bf16x4*)(vbase[dt] + (p0 ^ 8));
                    bf16x8 vf = __builtin_shufflevector(v0, v1, 0, 1, 2, 3, 4, 5, 6, 7);
                    acc[dt] = __builtin_amdgcn_mfma_f32_32x32x16_bf16(vf, pf, acc[dt], 0, 0, 0);
                }
            }
        }
    }

    // ---- epilogue: bf16 non-temporal partials ----
    lsum += __shfl_xor(lsum, 32, 64);
    unsigned short* Op = Opart + (size_t)((half << 5) | bh) * DHEAD * SEQ;
    #pragma unroll
    for (int dt = 0; dt < 2; ++dt)
        #pragma unroll
        for (int i = 0; i < 16; ++i) {
            const int dh = dt * 32 + (i & 3) + 8 * (i >> 2) + 4 * h;
            __builtin_nontemporal_store(f2bf(acc[dt][i]), Op + (size_t)dh * SEQ + qrow);
        }
    if (h == 0)
        __builtin_nontemporal_store(lsum, Lpart + (size_t)((half << 5) | bh) * SEQ + qrow);
}

// =====================================================================
// Combine: att[b][s][hd*64+dh] = (O0+O1)/(l0+l1), bf16 in/out. grid 512.
// =====================================================================
__global__ __launch_bounds__(256) void combine_kernel(
    const unsigned short* __restrict__ Opart, const float* __restrict__ Lpart,
    unsigned short* __restrict__ att)
{
    const int bid = blockIdx.x;
    const int bh = bid >> 4, qt = bid & 15;
    const int b = bh >> 4, hd = bh & 15;
    const int row0 = qt * 128;
    const int t = threadIdx.x;

    __shared__ float linv[128];
    __shared__ unsigned short Ot[128][68];

    if (t < 128) {
        float l = Lpart[(size_t)bh * SEQ + row0 + t]
                + Lpart[(size_t)(32 + bh) * SEQ + row0 + t];
        linv[t] = 1.0f / l;
    }
    __syncthreads();

    const int dh = t >> 2, qg = (t & 3) * 32;
    const unsigned short* p0 = Opart + ((size_t)bh * DHEAD + dh) * SEQ + row0 + qg;
    const unsigned short* p1 = Opart + ((size_t)(32 + bh) * DHEAD + dh) * SEQ + row0 + qg;
    #pragma unroll
    for (int j = 0; j < 4; ++j) {
        uint4 a = *(const uint4*)(p0 + j * 8);
        uint4 c = *(const uint4*)(p1 + j * 8);
        const unsigned int* au = (const unsigned int*)&a;
        const unsigned int* cu = (const unsigned int*)&c;
        #pragma unroll
        for (int d = 0; d < 4; ++d) {
            const int q = qg + j * 8 + d * 2;
            float a0 = __uint_as_float(au[d] << 16);
            float a1 = __uint_as_float(au[d] & 0xffff0000u);
            float c0 = __uint_as_float(cu[d] << 16);
            float c1 = __uint_as_float(cu[d] & 0xffff0000u);
            Ot[q + 0][dh] = f2bf((a0 + c0) * linv[q + 0]);
            Ot[q + 1][dh] = f2bf((a1 + c1) * linv[q + 1]);
        }
    }
    __syncthreads();
    {
        const int q = t >> 1, hf = t & 1;
        const unsigned short* src = &Ot[q][hf * 32];
        unsigned short* dst = att + ((size_t)b * SEQ + row0 + q) * DMODEL
                                  + hd * DHEAD + hf * 32;
        #pragma unroll
        for (int i = 0; i < 8; ++i)
            *(ushort4*)(dst + i * 4) = *(const ushort4*)(src + i * 4);
    }
}

// =====================================================================
// Output GEMM: out = att(bf16) @ Wot^T, f32 out. 128x128 tile, BK=64.
// 256 blocks, XCD-swizzled.
// =====================================================================
__global__ __launch_bounds__(256) void out_gemm_kernel(
    const unsigned short* __restrict__ A, const unsigned short* __restrict__ Bt,
    float* __restrict__ C)
{
    const int bid = blockIdx.x;
    const int sx = bid >> 3;
    const int m0 = ((bid & 7) * 4 + (sx >> 3)) * 128;
    const int n0 = (sx & 7) * 128;

    const int t = threadIdx.x, lane = t & 63, w = t >> 6;
    const int lg = lane >> 4, ln = lane & 15;
    const int wx = w & 1, wy = w >> 1;

    __shared__ __align__(16) unsigned short As[128 * 64];
    __shared__ __align__(16) unsigned short Bs[128 * 64];

    f32x4 acc[4][4] = {};

    for (int kk = 0; kk < DMODEL; kk += 64) {
        #pragma unroll
        for (int i = 0; i < 4; ++i) {
            int s = (w * 4 + i) * 64 + lane;
            int n = s >> 3, c = (s & 7) ^ (n & 7);
            gld_lds16(Bt + (size_t)(n0 + n) * DMODEL + kk + c * 8, Bs + (size_t)s * 8);
        }
        #pragma unroll
        for (int i = 0; i < 4; ++i) {
            int s = (w * 4 + i) * 64 + lane;
            int n = s >> 3, c = (s & 7) ^ (n & 7);
            gld_lds16(A + (size_t)(m0 + n) * DMODEL + kk + c * 8, As + (size_t)s * 8);
        }
        __syncthreads();
        #pragma unroll
        for (int ks = 0; ks < 2; ++ks) {
            bf16x8 af[4], bf[4];
            #pragma unroll
            for (int rb = 0; rb < 4; ++rb) {
                int r = wy * 64 + rb * 16 + ln;
                af[rb] = *(const bf16x8*)(As + r * 64 + (((ks * 4 + lg) ^ (r & 7)) * 8));
            }
            #pragma unroll
            for (int nb = 0; nb < 4; ++nb) {
                int n = wx * 64 + nb * 16 + ln;
                bf[nb] = *(const bf16x8*)(Bs + n * 64 + (((ks * 4 + lg) ^ (n & 7)) * 8));
            }
            #pragma unroll
            for (int rb = 0; rb < 4; ++rb)
                #pragma unroll
                for (int nb = 0; nb < 4; ++nb)
                    acc[rb][nb] = __builtin_amdgcn_mfma_f32_16x16x32_bf16(
                        af[rb], bf[nb], acc[rb][nb], 0, 0, 0);
        }
        __syncthreads();
    }

    #pragma unroll
    for (int rb = 0; rb < 4; ++rb)
        #pragma unroll
        for (int nb = 0; nb < 4; ++nb)
            #pragma unroll
            for (int r = 0; r < 4; ++r) {
                int grow = m0 + wy * 64 + rb * 16 + lg * 4 + r;
                int gcol = n0 + wx * 64 + nb * 16 + ln;
                C[(size_t)grow * DMODEL + gcol] = acc[rb][nb][r];
            }
}

extern "C" void kernel_launch(void* const* d_in, const int* in_sizes, int n_in,
                              void* d_out, int out_size, void* d_ws, size_t ws_size,
                              hipStream_t stream) {
    const float* q    = (const float*)d_in[0];
    const float* k    = (const float*)d_in[1];
    const float* v    = (const float*)d_in[2];
    const int*   mask = (const int*)  d_in[3];
    const float* Wq   = (const float*)d_in[4];
    const float* Wk   = (const float*)d_in[5];
    const float* Wv   = (const float*)d_in[6];
    const float* Wo   = (const float*)d_in[7];
    float* out = (float*)d_out;

    unsigned short* ws  = (unsigned short*)d_ws;
    const size_t n1 = (size_t)NB * NH * SEQ * DHEAD;      // 4,194,304 shorts
    const size_t nw = (size_t)NH * DHEAD * DMODEL;        // 1,048,576 shorts
    unsigned short* qh  = ws;
    unsigned short* kh  = qh + n1;
    unsigned short* vt  = kh + n1;                        // [bh][dh][seq]
    unsigned short* att = vt + n1;
    unsigned short* Wqt = att + n1;
    unsigned short* Wkt = Wqt + nw;
    unsigned short* Wvt = Wkt + nw;
    unsigned short* Wot = Wvt + nw;
    unsigned long long* mpack = (unsigned long long*)(Wot + nw);   // 1 MB
    // region A (aliased): qb/kb/vb (prep+proj) then Opart/Lpart (attn phase)
    unsigned short* regA = (unsigned short*)(mpack + (size_t)NB * SEQ * (SEQ / 64));
    unsigned short* qb = regA;
    unsigned short* kb = qb + n1;
    unsigned short* vb = kb + n1;
    unsigned short* Opart = regA;                         // 2*32*64*2048 bf16 = 16.8 MB
    float* Lpart = (float*)(Opart + (size_t)2 * 32 * DHEAD * SEQ);  // 0.5 MB

    prep_kernel<<<dim3(8192), 256, 0, stream>>>(
        mask, mpack, Wq, Wk, Wv, Wqt, Wkt, Wvt, Wo, Wot, q, k, v, qb, kb, vb);
    proj_gemm_kernel<<<dim3(768), 256, 0, stream>>>(qb, kb, vb, Wqt, Wkt, Wvt, qh, kh, vt);
    attn_kernel<<<dim3(1024), 256, 0, stream>>>(qh, kh, vt, mpack, Opart, Lpart);
    combine_kernel<<<dim3(512), 256, 0, stream>>>(Opart, Lpart, att);
    out_gemm_kernel<<<dim3(256), 256, 0, stream>>>(att, Wot, out);
}